// Round 1
// baseline (506.362 us; speedup 1.0000x reference)
//
#include <hip/hip_runtime.h>
#include <hip/hip_fp16.h>

#define NN 100000
#define NE 1600000
#define NG 512
#define F  32

#define BSH    8                              // 256 dst-nodes per bucket
#define BNODES 256
#define NB     ((NN + BNODES - 1) / BNODES)   // 391
#define CAP    5120                           // slots/bucket (mean 4096, sigma 64 -> safe)

// ---- deg: edge-parallel exact degree histogram (int atomics into 400KB L2-resident) ----
__global__ void k_deg(const int* __restrict__ dst, int* __restrict__ deg) {
    int t = blockIdx.x * blockDim.x + threadIdx.x;
    int e = t * 4;
    if (e + 3 < NE) {
        int4 d = *(const int4*)(dst + e);
        atomicAdd(&deg[d.x], 1);
        atomicAdd(&deg[d.y], 1);
        atomicAdd(&deg[d.z], 1);
        atomicAdd(&deg[d.w], 1);
    } else {
        for (; e < NE; ++e) atomicAdd(&deg[dst[e]], 1);
    }
}

// ---- nodeinit: per-bucket prefix scan of exact degrees -> rowpack/wcur/dinv/xd ----
__global__ void k_nodeinit(const int* __restrict__ deg, const float* __restrict__ x,
                           int* __restrict__ rowpack, int* __restrict__ wcur,
                           float* __restrict__ dinv, float4* __restrict__ xd) {
    __shared__ int wsum[4];
    int b = blockIdx.x, tid = threadIdx.x;
    int n = (b << BSH) + tid;
    int c = (n < NN) ? deg[n] : 0;
    int v = c;
#pragma unroll
    for (int o = 1; o < 64; o <<= 1) {
        int t = __shfl_up(v, o, 64);
        if ((tid & 63) >= o) v += t;
    }
    if ((tid & 63) == 63) wsum[tid >> 6] = v;
    __syncthreads();
    int add = 0;
    for (int w = 0; w < (tid >> 6); ++w) add += wsum[w];
    int excl = v + add - c;
    if (n < NN) {
        int pos = b * CAP + excl;                 // absolute csr row start (exact degree rows)
        rowpack[n] = (pos << 10) | c;             // pos < 2,002,000 < 2^21, deg < 1024
        wcur[n] = pos;
        float d = rsqrtf((float)c + 1.0f);
        dinv[n] = d;
        xd[n] = make_float4(d * x[n * 3 + 0], d * x[n * 3 + 1], d * x[n * 3 + 2], d);
    }
}

// ---- edge: single edge pass. csr append (atomic cursor) + layer-1 scatter-aggregate ----
// agg[dst] += xd[src]  (3 f32 atomics into 1.6MB L2-resident array)
__global__ void k_edge(const int* __restrict__ src, const int* __restrict__ dst,
                       const float4* __restrict__ xd,
                       int* __restrict__ wcur, int* __restrict__ csr,
                       float* __restrict__ agg) {
    int t = blockIdx.x * blockDim.x + threadIdx.x;
    int e = t * 4;
    if (e + 3 < NE) {
        int4 s = *(const int4*)(src + e);
        int4 d = *(const int4*)(dst + e);
        {
            float4 v = xd[s.x];
            int p = atomicAdd(&wcur[d.x], 1);
            csr[p] = s.x;
            atomicAdd(&agg[4 * d.x + 0], v.x);
            atomicAdd(&agg[4 * d.x + 1], v.y);
            atomicAdd(&agg[4 * d.x + 2], v.z);
        }
        {
            float4 v = xd[s.y];
            int p = atomicAdd(&wcur[d.y], 1);
            csr[p] = s.y;
            atomicAdd(&agg[4 * d.y + 0], v.x);
            atomicAdd(&agg[4 * d.y + 1], v.y);
            atomicAdd(&agg[4 * d.y + 2], v.z);
        }
        {
            float4 v = xd[s.z];
            int p = atomicAdd(&wcur[d.z], 1);
            csr[p] = s.z;
            atomicAdd(&agg[4 * d.z + 0], v.x);
            atomicAdd(&agg[4 * d.z + 1], v.y);
            atomicAdd(&agg[4 * d.z + 2], v.z);
        }
        {
            float4 v = xd[s.w];
            int p = atomicAdd(&wcur[d.w], 1);
            csr[p] = s.w;
            atomicAdd(&agg[4 * d.w + 0], v.x);
            atomicAdd(&agg[4 * d.w + 1], v.y);
            atomicAdd(&agg[4 * d.w + 2], v.z);
        }
    } else {
        for (; e < NE; ++e) {
            int sv = src[e], dv = dst[e];
            float4 v = xd[sv];
            int p = atomicAdd(&wcur[dv], 1);
            csr[p] = sv;
            atomicAdd(&agg[4 * dv + 0], v.x);
            atomicAdd(&agg[4 * dv + 1], v.y);
            atomicAdd(&agg[4 * dv + 2], v.z);
        }
    }
}

// ---- l1: node-parallel layer-1 finish. g1[n] = dinv*relu((dinv*(agg+xd_self))@W1+b1) fp16
__global__ void k_l1(const float4* __restrict__ aggv, const float4* __restrict__ xd,
                     const float* __restrict__ W1, const float* __restrict__ b1,
                     __half2* __restrict__ g1) {
    __shared__ float W1s[3 * F];
    __shared__ float b1s[F];
    int tid = threadIdx.x;
    if (tid < 3 * F) W1s[tid] = W1[tid];
    if (tid < F) b1s[tid] = b1[tid];
    __syncthreads();
    int n = blockIdx.x * 256 + tid;
    if (n >= NN) return;
    float4 a = aggv[n];
    float4 sf = xd[n];
    float dn = sf.w;
    float cx = dn * (a.x + sf.x), cy = dn * (a.y + sf.y), cz = dn * (a.z + sf.z);
    __half2 tmp[16];
#pragma unroll
    for (int j = 0; j < 16; ++j) {
        int f0 = 2 * j, f1 = 2 * j + 1;
        float v0 = cx * W1s[f0] + cy * W1s[F + f0] + cz * W1s[2 * F + f0] + b1s[f0];
        float v1 = cx * W1s[f1] + cy * W1s[F + f1] + cz * W1s[2 * F + f1] + b1s[f1];
        tmp[j] = __floats2half2_rn(dn * fmaxf(v0, 0.0f), dn * fmaxf(v1, 0.0f));
    }
    uint4* hv = (uint4*)(g1 + (size_t)n * 16);
    const uint4* tv = (const uint4*)tmp;
    hv[0] = tv[0]; hv[1] = tv[1]; hv[2] = tv[2]; hv[3] = tv[3];
}

// ---- gather2p: gather g1 + fp32 t + proj2(W2)+relu + per-block pool -> gsum ----
__global__ void k_gather2p(const int* __restrict__ rowpack, const int* __restrict__ csr,
                           const __half2* __restrict__ g1, const float* __restrict__ dinv,
                           const int* __restrict__ batch,
                           const float* __restrict__ W2, const float* __restrict__ b2,
                           float* __restrict__ gsum) {
    __shared__ float W2s[F * F];
    __shared__ float b2s[F];
    __shared__ float ts[16][F];
    __shared__ float hs[16][F];
    __shared__ int bat[16];
    int tid = threadIdx.x;
    int nb = blockIdx.x * 16;
    for (int i = tid; i < F * F; i += 256) W2s[i] = W2[i];
    if (tid < F) b2s[tid] = b2[tid];
    if (tid < 16) bat[tid] = batch[nb + tid];
    int nl = tid >> 4, j = tid & 15;
    int n = nb + nl;
    {
        int pack = rowpack[n];
        int beg = pack >> 10, end = beg + (pack & 1023);
        float ax = 0.0f, ay = 0.0f;
        int e = beg;
        for (; e + 7 < end; e += 8) {
            int s0 = csr[e],     s1 = csr[e + 1], s2 = csr[e + 2], s3 = csr[e + 3];
            int s4 = csr[e + 4], s5 = csr[e + 5], s6 = csr[e + 6], s7 = csr[e + 7];
            float2 v0 = __half22float2(g1[s0 * 16 + j]);
            float2 v1 = __half22float2(g1[s1 * 16 + j]);
            float2 v2 = __half22float2(g1[s2 * 16 + j]);
            float2 v3 = __half22float2(g1[s3 * 16 + j]);
            float2 v4 = __half22float2(g1[s4 * 16 + j]);
            float2 v5 = __half22float2(g1[s5 * 16 + j]);
            float2 v6 = __half22float2(g1[s6 * 16 + j]);
            float2 v7 = __half22float2(g1[s7 * 16 + j]);
            ax += ((v0.x + v1.x) + (v2.x + v3.x)) + ((v4.x + v5.x) + (v6.x + v7.x));
            ay += ((v0.y + v1.y) + (v2.y + v3.y)) + ((v4.y + v5.y) + (v6.y + v7.y));
        }
        for (; e + 3 < end; e += 4) {
            int s0 = csr[e], s1 = csr[e + 1], s2 = csr[e + 2], s3 = csr[e + 3];
            float2 v0 = __half22float2(g1[s0 * 16 + j]);
            float2 v1 = __half22float2(g1[s1 * 16 + j]);
            float2 v2 = __half22float2(g1[s2 * 16 + j]);
            float2 v3 = __half22float2(g1[s3 * 16 + j]);
            ax += (v0.x + v1.x) + (v2.x + v3.x);
            ay += (v0.y + v1.y) + (v2.y + v3.y);
        }
        for (; e < end; ++e) {
            float2 v = __half22float2(g1[csr[e] * 16 + j]);
            ax += v.x; ay += v.y;
        }
        float dn = dinv[n];
        float2 sf = __half22float2(g1[n * 16 + j]);
        ts[nl][2 * j]     = dn * (ax + sf.x);
        ts[nl][2 * j + 1] = dn * (ay + sf.y);
    }
    __syncthreads();
    {
        int f = tid & 31;
        int nn0 = tid >> 5;           // 0..7
#pragma unroll
        for (int pass = 0; pass < 2; ++pass) {
            int nn = nn0 + pass * 8;
            float acc = b2s[f];
#pragma unroll
            for (int k = 0; k < F; ++k) acc += ts[nn][k] * W2s[k * F + f];
            hs[nn][f] = fmaxf(acc, 0.0f);
        }
    }
    __syncthreads();
    if (tid < F) {
        int g0 = bat[0], gmax = bat[15];
        for (int g = g0; g <= gmax; ++g) {
            float s = 0.0f;
#pragma unroll
            for (int i = 0; i < 16; ++i) if (bat[i] == g) s += hs[i][tid];
            atomicAdd(&gsum[g * F + tid], s);
        }
    }
}

// ---- head: out[g] = (gsum[g]/max(cnt,1)) @ Wl + bl ----
__global__ void k_head(const float* __restrict__ gsum, const int* __restrict__ batch,
                       const float* __restrict__ Wl, const float* __restrict__ bl,
                       float* __restrict__ out) {
    int g = blockIdx.x * blockDim.x + threadIdx.x;
    if (g >= NG) return;
    int lo = 0, hi = NN;
    while (lo < hi) { int m = (lo + hi) >> 1; if (batch[m] < g) lo = m + 1; else hi = m; }
    int s = lo;
    lo = 0; hi = NN;
    while (lo < hi) { int m = (lo + hi) >> 1; if (batch[m] < g + 1) lo = m + 1; else hi = m; }
    float inv = 1.0f / fmaxf((float)(lo - s), 1.0f);
    float a0 = 0.0f, a1 = 0.0f;
#pragma unroll
    for (int k = 0; k < F; ++k) {
        float m = gsum[g * F + k] * inv;
        a0 += m * Wl[k * 2 + 0];
        a1 += m * Wl[k * 2 + 1];
    }
    out[g * 2 + 0] = a0 + bl[0];
    out[g * 2 + 1] = a1 + bl[1];
}

extern "C" void kernel_launch(void* const* d_in, const int* in_sizes, int n_in,
                              void* d_out, int out_size, void* d_ws, size_t ws_size,
                              hipStream_t stream) {
    const float* x     = (const float*)d_in[0];
    const int*   eidx  = (const int*)d_in[1];   // int32 per harness contract
    const int*   batch = (const int*)d_in[2];
    const float* W1    = (const float*)d_in[3];
    const float* b1    = (const float*)d_in[4];
    const float* W2    = (const float*)d_in[5];
    const float* b2    = (const float*)d_in[6];
    const float* Wl    = (const float*)d_in[7];
    const float* bl    = (const float*)d_in[8];
    float*       out   = (float*)d_out;

    const int* src = eidx;
    const int* dst = eidx + NE;

    // ---- workspace layout, 128B-aligned chunks ----
    char* base = (char*)d_ws;
    size_t off = 0;
    auto alloc = [&](size_t bytes) {
        void* p = base + off;
        off = (off + bytes + 127) & ~(size_t)127;
        return p;
    };
    // deg + gsum + agg contiguous -> single memset (2.07 MB)
    size_t zbytes = (size_t)NN * sizeof(int) + (size_t)NG * F * sizeof(float)
                  + (size_t)NN * 4 * sizeof(float);
    int*    deg  = (int*)alloc(zbytes);
    float*  gsum = (float*)(deg + NN);
    float*  agg  = gsum + (size_t)NG * F;
    int*    rowpack = (int*)alloc(NN * sizeof(int));
    int*    wcur    = (int*)alloc(NN * sizeof(int));
    float*  dinv    = (float*)alloc(NN * sizeof(float));
    float4* xd      = (float4*)alloc(NN * sizeof(float4));
    int*    csr     = (int*)alloc((size_t)NB * CAP * sizeof(int));
    __half2* g1     = (__half2*)alloc((size_t)NN * 16 * sizeof(__half2));

    const int B = 256;
    const int gE4  = (NE / 4 + B - 1) / B;   // 1563
    const int gG16 = NN / 16;                // 6250, exact

    hipMemsetAsync(deg, 0, zbytes, stream);

    // ---- CSR build (2 atomic passes) + fused layer-1 scatter-aggregate ----
    k_deg     <<<gE4, B, 0, stream>>>(dst, deg);
    k_nodeinit<<<NB,  B, 0, stream>>>(deg, x, rowpack, wcur, dinv, xd);
    k_edge    <<<gE4, B, 0, stream>>>(src, dst, xd, wcur, csr, agg);
    k_l1      <<<NB,  B, 0, stream>>>((const float4*)agg, xd, W1, b1, g1);

    // ---- layer 2 gather + proj2 + relu + pool (fused) ----
    k_gather2p<<<gG16, B, 0, stream>>>(rowpack, csr, g1, dinv, batch, W2, b2, gsum);

    // ---- head ----
    k_head<<<(NG + B - 1) / B, B, 0, stream>>>(gsum, batch, Wl, bl, out);
}

// Round 4
// 159.570 us; speedup vs baseline: 3.1733x; 3.1733x over previous
//
#include <hip/hip_runtime.h>
#include <hip/hip_fp16.h>

#define NN 100000
#define NE 1600000
#define NG 512
#define F  32

#define BSH    8                              // 256 dst-nodes per bucket
#define BNODES 256
#define NB     ((NN + BNODES - 1) / BNODES)   // 391
#define CAP    5120                           // slots/bucket (mean 4092, sigma 64 -> safe)
#define PCHUNK 4096
#define EPT    8                              // edges per thread (PCHUNK/512)
#define NWGP   ((NE + PCHUNK - 1) / PCHUNK)   // 391

// ---- partition: in-LDS counting sort per chunk -> coalesced bucket-run writes ----
__global__ void k_partition(const int* __restrict__ src, const int* __restrict__ dst,
                            int* __restrict__ cursor, int* __restrict__ part) {
    __shared__ int   s_cnt[NB];      // hist, then reused as rank counter
    __shared__ int   s_lstart[NB];
    __shared__ int   s_base[NB];
    __shared__ int   wsum[8];
    __shared__ int   lsort[PCHUNK];
    __shared__ short lbkt[PCHUNK];
    int tid = threadIdx.x;
    for (int i = tid; i < NB; i += 512) s_cnt[i] = 0;
    __syncthreads();
    int e0 = blockIdx.x * PCHUNK;
    int rem = NE - e0;
    int pk[EPT]; short bk[EPT];
    int m = 0;
    if (rem >= PCHUNK) {
        // full chunk: 2x int4 vector loads per thread (16B/lane, fully coalesced)
#pragma unroll
        for (int h = 0; h < 2; ++h) {
            int e = e0 + h * 2048 + tid * 4;
            int4 s4 = *(const int4*)(src + e);
            int4 d4 = *(const int4*)(dst + e);
            int ss[4] = {s4.x, s4.y, s4.z, s4.w};
            int dd[4] = {d4.x, d4.y, d4.z, d4.w};
#pragma unroll
            for (int u = 0; u < 4; ++u) {
                pk[m] = (ss[u] << 8) | (dd[u] & (BNODES - 1));
                bk[m] = (short)(dd[u] >> BSH);
                atomicAdd(&s_cnt[bk[m]], 1);
                ++m;
            }
        }
    } else {
        // tail chunk (2560 edges): scalar guarded path
#pragma unroll
        for (int k = 0; k < EPT; ++k) {
            int e = e0 + tid + k * 512;
            if (e < NE) {
                int d = dst[e];
                pk[m] = (src[e] << 8) | (d & (BNODES - 1));
                bk[m] = (short)(d >> BSH);
                atomicAdd(&s_cnt[bk[m]], 1);
                ++m;
            }
        }
    }
    __syncthreads();
    int cv = (tid < NB) ? s_cnt[tid] : 0;
    int v = cv;
#pragma unroll
    for (int o = 1; o < 64; o <<= 1) {
        int t = __shfl_up(v, o, 64);
        if ((tid & 63) >= o) v += t;
    }
    if ((tid & 63) == 63) wsum[tid >> 6] = v;
    __syncthreads();
    int add = 0;
    for (int w = 0; w < (tid >> 6); ++w) add += wsum[w];
    int excl = v + add - cv;
    if (tid < NB) {
        s_lstart[tid] = excl;
        if (cv) s_base[tid] = tid * CAP + atomicAdd(&cursor[tid], cv);
        s_cnt[tid] = 0;   // reuse as rank counter
    }
    __syncthreads();
    for (int k = 0; k < m; ++k) {
        int b = bk[k];
        int r = s_lstart[b] + atomicAdd(&s_cnt[b], 1);
        lsort[r] = pk[k];
        lbkt[r]  = (short)b;
    }
    __syncthreads();
    int cnt = min(rem, PCHUNK);
    for (int i = tid; i < cnt; i += 512) {
        int b = lbkt[i];
        part[s_base[b] + (i - s_lstart[b])] = lsort[i];   // coalesced per-bucket runs
    }
}

// ---- fill2a: per-bucket histogram + wave-scan -> rowpack[(pos<<10)|deg], dinv, xd ----
__global__ void k_fill2a(const int* __restrict__ part, const int* __restrict__ cursor,
                         const float* __restrict__ x,
                         int* __restrict__ rowpack, float* __restrict__ dinv,
                         float4* __restrict__ xd) {
    __shared__ int hcnt[BNODES];
    __shared__ int wsum[4];
    int b = blockIdx.x, tid = threadIdx.x;
    int node0 = b << BSH;
    int s0 = b * CAP;
    int ec = cursor[b];
    hcnt[tid] = 0;
    __syncthreads();
    int ctail = ec & ~3;
    for (int i = tid * 4; i < ctail; i += 1024) {      // int4 vector hist pass
        int4 p = *(const int4*)(part + s0 + i);
        atomicAdd(&hcnt[p.x & (BNODES - 1)], 1);
        atomicAdd(&hcnt[p.y & (BNODES - 1)], 1);
        atomicAdd(&hcnt[p.z & (BNODES - 1)], 1);
        atomicAdd(&hcnt[p.w & (BNODES - 1)], 1);
    }
    if (tid < ec - ctail) atomicAdd(&hcnt[part[s0 + ctail + tid] & (BNODES - 1)], 1);
    __syncthreads();
    int c = hcnt[tid];
    int v = c;
#pragma unroll
    for (int o = 1; o < 64; o <<= 1) {
        int t = __shfl_up(v, o, 64);
        if ((tid & 63) >= o) v += t;
    }
    if ((tid & 63) == 63) wsum[tid >> 6] = v;
    __syncthreads();
    int add = 0;
    for (int w = 0; w < (tid >> 6); ++w) add += wsum[w];
    int excl = v + add - c;
    int n = node0 + tid;
    if (n < NN) {
        rowpack[n] = ((s0 + excl) << 10) | c;
        float d = rsqrtf((float)c + 1.0f);
        dinv[n] = d;
        xd[n] = make_float4(d * x[n * 3 + 0], d * x[n * 3 + 1], d * x[n * 3 + 2], d);
    }
}

// ---- fill2b: LDS-staged csr scatter + coalesced write-out + fused layer 1 ----
// g1[n] = dinv[n] * relu( (dinv[n]*(sum_e xd[s]+xd[n])) @ W1 + b1 )  fp16
__global__ void k_fill2b(const int* __restrict__ part, const int* __restrict__ cursor,
                         const int* __restrict__ rowpack, const float4* __restrict__ xd,
                         const float* __restrict__ W1, const float* __restrict__ b1,
                         int* __restrict__ csr, __half2* __restrict__ g1) {
    __shared__ __align__(16) int lcsr[CAP];
    __shared__ int off[BNODES];
    __shared__ float W1s[3 * F];
    __shared__ float b1s[F];
    int b = blockIdx.x, tid = threadIdx.x;
    int node0 = b << BSH;
    int s0 = b * CAP;
    int cnt = cursor[b];
    if (tid < 3 * F) W1s[tid] = W1[tid];
    if (tid < F) b1s[tid] = b1[tid];
    int n = node0 + tid;
    int pack = (n < NN) ? rowpack[n] : (s0 << 10);
    off[tid] = (pack >> 10) - s0;
    __syncthreads();
    int ctail = cnt & ~3;
    for (int i = tid * 4; i < ctail; i += 1024) {      // int4 vector rank-scatter
        int4 p = *(const int4*)(part + s0 + i);
        { int pos = atomicAdd(&off[p.x & (BNODES - 1)], 1); lcsr[pos] = p.x >> 8; }
        { int pos = atomicAdd(&off[p.y & (BNODES - 1)], 1); lcsr[pos] = p.y >> 8; }
        { int pos = atomicAdd(&off[p.z & (BNODES - 1)], 1); lcsr[pos] = p.z >> 8; }
        { int pos = atomicAdd(&off[p.w & (BNODES - 1)], 1); lcsr[pos] = p.w >> 8; }
    }
    if (tid < cnt - ctail) {
        int p = part[s0 + ctail + tid];
        int pos = atomicAdd(&off[p & (BNODES - 1)], 1);
        lcsr[pos] = p >> 8;
    }
    __syncthreads();
    for (int i = tid * 4; i < ctail; i += 1024)        // int4 coalesced write-out
        *(int4*)(csr + s0 + i) = *(const int4*)(lcsr + i);
    if (tid < cnt - ctail) csr[s0 + ctail + tid] = lcsr[ctail + tid];
    if (n < NN) {
        int deg = pack & 1023;
        int beg = (pack >> 10) - s0;
        int end = beg + deg;
        float ax = 0.0f, ay = 0.0f, az = 0.0f;
        int e = beg;
        for (; e + 7 < end; e += 8) {
#pragma unroll
            for (int u = 0; u < 8; ++u) {
                float4 v = xd[lcsr[e + u]];
                ax += v.x; ay += v.y; az += v.z;
            }
        }
        for (; e < end; ++e) {
            float4 v = xd[lcsr[e]];
            ax += v.x; ay += v.y; az += v.z;
        }
        float4 sf = xd[n];
        float dn = sf.w;
        float cx = dn * (ax + sf.x), cy = dn * (ay + sf.y), cz = dn * (az + sf.z);
        __half2 tmp[16];
#pragma unroll
        for (int j = 0; j < 16; ++j) {
            int f0 = 2 * j, f1 = 2 * j + 1;
            float v0 = cx * W1s[f0] + cy * W1s[F + f0] + cz * W1s[2 * F + f0] + b1s[f0];
            float v1 = cx * W1s[f1] + cy * W1s[F + f1] + cz * W1s[2 * F + f1] + b1s[f1];
            tmp[j] = __floats2half2_rn(dn * fmaxf(v0, 0.0f), dn * fmaxf(v1, 0.0f));
        }
        uint4* hv = (uint4*)(g1 + (size_t)n * 16);
        const uint4* tv = (const uint4*)tmp;
        hv[0] = tv[0]; hv[1] = tv[1]; hv[2] = tv[2]; hv[3] = tv[3];
    }
}

// ---- gather2p: gather g1 + fp32 t + proj2(W2)+relu + per-block pool -> gsum ----
__global__ void k_gather2p(const int* __restrict__ rowpack, const int* __restrict__ csr,
                           const __half2* __restrict__ g1, const float* __restrict__ dinv,
                           const int* __restrict__ batch,
                           const float* __restrict__ W2, const float* __restrict__ b2,
                           float* __restrict__ gsum) {
    __shared__ __align__(16) float W2s[F * F];
    __shared__ __align__(16) float b2s[F];
    __shared__ float ts[16][F];
    __shared__ float hs[16][F];
    __shared__ int bat[16];
    int tid = threadIdx.x;
    int nb = blockIdx.x * 16;
    ((float4*)W2s)[tid] = ((const float4*)W2)[tid];    // 256 threads x float4 = 1024 floats
    if (tid < F / 4) ((float4*)b2s)[tid] = ((const float4*)b2)[tid];
    if (tid < 16) bat[tid] = batch[nb + tid];
    int nl = tid >> 4, j = tid & 15;
    int n = nb + nl;
    {
        int pack = rowpack[n];
        int beg = pack >> 10, end = beg + (pack & 1023);
        float ax = 0.0f, ay = 0.0f;
        int e = beg;
        for (; e + 7 < end; e += 8) {
            int s0 = csr[e],     s1 = csr[e + 1], s2 = csr[e + 2], s3 = csr[e + 3];
            int s4 = csr[e + 4], s5 = csr[e + 5], s6 = csr[e + 6], s7 = csr[e + 7];
            float2 v0 = __half22float2(g1[s0 * 16 + j]);
            float2 v1 = __half22float2(g1[s1 * 16 + j]);
            float2 v2 = __half22float2(g1[s2 * 16 + j]);
            float2 v3 = __half22float2(g1[s3 * 16 + j]);
            float2 v4 = __half22float2(g1[s4 * 16 + j]);
            float2 v5 = __half22float2(g1[s5 * 16 + j]);
            float2 v6 = __half22float2(g1[s6 * 16 + j]);
            float2 v7 = __half22float2(g1[s7 * 16 + j]);
            ax += ((v0.x + v1.x) + (v2.x + v3.x)) + ((v4.x + v5.x) + (v6.x + v7.x));
            ay += ((v0.y + v1.y) + (v2.y + v3.y)) + ((v4.y + v5.y) + (v6.y + v7.y));
        }
        for (; e + 3 < end; e += 4) {
            int s0 = csr[e], s1 = csr[e + 1], s2 = csr[e + 2], s3 = csr[e + 3];
            float2 v0 = __half22float2(g1[s0 * 16 + j]);
            float2 v1 = __half22float2(g1[s1 * 16 + j]);
            float2 v2 = __half22float2(g1[s2 * 16 + j]);
            float2 v3 = __half22float2(g1[s3 * 16 + j]);
            ax += (v0.x + v1.x) + (v2.x + v3.x);
            ay += (v0.y + v1.y) + (v2.y + v3.y);
        }
        for (; e < end; ++e) {
            float2 v = __half22float2(g1[csr[e] * 16 + j]);
            ax += v.x; ay += v.y;
        }
        float dn = dinv[n];
        float2 sf = __half22float2(g1[n * 16 + j]);
        ts[nl][2 * j]     = dn * (ax + sf.x);
        ts[nl][2 * j + 1] = dn * (ay + sf.y);
    }
    __syncthreads();
    {
        int f = tid & 31;
        int nn0 = tid >> 5;           // 0..7
#pragma unroll
        for (int pass = 0; pass < 2; ++pass) {
            int nn = nn0 + pass * 8;
            float acc = b2s[f];
#pragma unroll
            for (int k = 0; k < F; ++k) acc += ts[nn][k] * W2s[k * F + f];
            hs[nn][f] = fmaxf(acc, 0.0f);
        }
    }
    __syncthreads();
    if (tid < F) {
        int g0 = bat[0], gmax = bat[15];
        for (int g = g0; g <= gmax; ++g) {
            float s = 0.0f;
#pragma unroll
            for (int i = 0; i < 16; ++i) if (bat[i] == g) s += hs[i][tid];
            atomicAdd(&gsum[g * F + tid], s);
        }
    }
}

// ---- head: out[g] = (gsum[g]/max(cnt,1)) @ Wl + bl ----
__global__ void k_head(const float* __restrict__ gsum, const int* __restrict__ batch,
                       const float* __restrict__ Wl, const float* __restrict__ bl,
                       float* __restrict__ out) {
    int g = blockIdx.x * blockDim.x + threadIdx.x;
    if (g >= NG) return;
    int lo = 0, hi = NN;
    while (lo < hi) { int m = (lo + hi) >> 1; if (batch[m] < g) lo = m + 1; else hi = m; }
    int s = lo;
    lo = 0; hi = NN;
    while (lo < hi) { int m = (lo + hi) >> 1; if (batch[m] < g + 1) lo = m + 1; else hi = m; }
    float inv = 1.0f / fmaxf((float)(lo - s), 1.0f);
    float a0 = 0.0f, a1 = 0.0f;
#pragma unroll
    for (int k = 0; k < F; ++k) {
        float m = gsum[g * F + k] * inv;
        a0 += m * Wl[k * 2 + 0];
        a1 += m * Wl[k * 2 + 1];
    }
    out[g * 2 + 0] = a0 + bl[0];
    out[g * 2 + 1] = a1 + bl[1];
}

extern "C" void kernel_launch(void* const* d_in, const int* in_sizes, int n_in,
                              void* d_out, int out_size, void* d_ws, size_t ws_size,
                              hipStream_t stream) {
    const float* x     = (const float*)d_in[0];
    const int*   eidx  = (const int*)d_in[1];   // int32 per harness contract
    const int*   batch = (const int*)d_in[2];
    const float* W1    = (const float*)d_in[3];
    const float* b1    = (const float*)d_in[4];
    const float* W2    = (const float*)d_in[5];
    const float* b2    = (const float*)d_in[6];
    const float* Wl    = (const float*)d_in[7];
    const float* bl    = (const float*)d_in[8];
    float*       out   = (float*)d_out;

    const int* src = eidx;
    const int* dst = eidx + NE;

    // ---- workspace layout, 128B-aligned chunks ----
    char* base = (char*)d_ws;
    size_t off = 0;
    auto alloc = [&](size_t bytes) {
        void* p = base + off;
        off = (off + bytes + 127) & ~(size_t)127;
        return p;
    };
    // cursor + gsum contiguous -> single memset
    int*     cursor  = (int*)alloc(NB * sizeof(int) + (size_t)NG * F * sizeof(float));
    float*   gsum    = (float*)(cursor + NB);
    int*     rowpack = (int*)alloc(NN * sizeof(int));
    int*     part    = (int*)alloc((size_t)NB * CAP * sizeof(int));
    int*     csr     = (int*)alloc((size_t)NB * CAP * sizeof(int));
    float*   dinv    = (float*)alloc(NN * sizeof(float));
    float4*  xd      = (float4*)alloc(NN * sizeof(float4));
    __half2* g1      = (__half2*)alloc((size_t)NN * 16 * sizeof(__half2));

    const int B = 256;
    const int gG16 = NN / 16;   // 6250, exact

    hipMemsetAsync(cursor, 0, NB * sizeof(int) + (size_t)NG * F * sizeof(float), stream);

    // ---- CSR build ----
    k_partition<<<NWGP, 512, 0, stream>>>(src, dst, cursor, part);
    k_fill2a   <<<NB,   B,   0, stream>>>(part, cursor, x, rowpack, dinv, xd);
    k_fill2b   <<<NB,   B,   0, stream>>>(part, cursor, rowpack, xd, W1, b1, csr, g1);

    // ---- layer 2 gather + proj2 + relu + pool (fused) ----
    k_gather2p<<<gG16, B, 0, stream>>>(rowpack, csr, g1, dinv, batch, W2, b2, gsum);

    // ---- head ----
    k_head<<<(NG + B - 1) / B, B, 0, stream>>>(gsum, batch, Wl, bl, out);
}

// Round 5
// 156.777 us; speedup vs baseline: 3.2298x; 1.0178x over previous
//
#include <hip/hip_runtime.h>
#include <hip/hip_fp16.h>

#define NN 100000
#define NE 1600000
#define NG 512
#define F  32

#define BSH    8                              // 256 dst-nodes per bucket
#define BNODES 256
#define NB     ((NN + BNODES - 1) / BNODES)   // 391
#define CAP    5120                           // slots/bucket (mean 4092, sigma 64 -> safe)
#define PCHUNK 4096
#define EPT    8                              // edges per thread (PCHUNK/512)
#define NWGP   ((NE + PCHUNK - 1) / PCHUNK)   // 391

// ---- partition: in-LDS counting sort per chunk -> coalesced bucket-run writes ----
__global__ void k_partition(const int* __restrict__ src, const int* __restrict__ dst,
                            int* __restrict__ cursor, int* __restrict__ part) {
    __shared__ int   s_cnt[NB];      // hist, then reused as rank counter
    __shared__ int   s_lstart[NB];
    __shared__ int   s_base[NB];
    __shared__ int   wsum[8];
    __shared__ int   lsort[PCHUNK];
    __shared__ short lbkt[PCHUNK];
    int tid = threadIdx.x;
    for (int i = tid; i < NB; i += 512) s_cnt[i] = 0;
    __syncthreads();
    int e0 = blockIdx.x * PCHUNK;
    int rem = NE - e0;
    int pk[EPT]; short bk[EPT];
    int m = 0;
    if (rem >= PCHUNK) {
        // full chunk: 2x int4 vector loads per thread (16B/lane, fully coalesced)
#pragma unroll
        for (int h = 0; h < 2; ++h) {
            int e = e0 + h * 2048 + tid * 4;
            int4 s4 = *(const int4*)(src + e);
            int4 d4 = *(const int4*)(dst + e);
            int ss[4] = {s4.x, s4.y, s4.z, s4.w};
            int dd[4] = {d4.x, d4.y, d4.z, d4.w};
#pragma unroll
            for (int u = 0; u < 4; ++u) {
                pk[m] = (ss[u] << 8) | (dd[u] & (BNODES - 1));
                bk[m] = (short)(dd[u] >> BSH);
                atomicAdd(&s_cnt[bk[m]], 1);
                ++m;
            }
        }
    } else {
        // tail chunk (2560 edges): scalar guarded path
#pragma unroll
        for (int k = 0; k < EPT; ++k) {
            int e = e0 + tid + k * 512;
            if (e < NE) {
                int d = dst[e];
                pk[m] = (src[e] << 8) | (d & (BNODES - 1));
                bk[m] = (short)(d >> BSH);
                atomicAdd(&s_cnt[bk[m]], 1);
                ++m;
            }
        }
    }
    __syncthreads();
    int cv = (tid < NB) ? s_cnt[tid] : 0;
    int v = cv;
#pragma unroll
    for (int o = 1; o < 64; o <<= 1) {
        int t = __shfl_up(v, o, 64);
        if ((tid & 63) >= o) v += t;
    }
    if ((tid & 63) == 63) wsum[tid >> 6] = v;
    __syncthreads();
    int add = 0;
    for (int w = 0; w < (tid >> 6); ++w) add += wsum[w];
    int excl = v + add - cv;
    if (tid < NB) {
        s_lstart[tid] = excl;
        if (cv) s_base[tid] = tid * CAP + atomicAdd(&cursor[tid], cv);
        s_cnt[tid] = 0;   // reuse as rank counter
    }
    __syncthreads();
    for (int k = 0; k < m; ++k) {
        int b = bk[k];
        int r = s_lstart[b] + atomicAdd(&s_cnt[b], 1);
        lsort[r] = pk[k];
        lbkt[r]  = (short)b;
    }
    __syncthreads();
    int cnt = min(rem, PCHUNK);
    for (int i = tid; i < cnt; i += 512) {
        int b = lbkt[i];
        part[s_base[b] + (i - s_lstart[b])] = lsort[i];   // coalesced per-bucket runs
    }
}

// ---- build: hist + scan -> rowpack/dinv/xd, then rank-scatter + coalesced csr write ----
// (merged fill2a + fill2b's scatter; part's 2nd read is cache-hot, one kernel boundary gone)
__global__ void k_build(const int* __restrict__ part, const int* __restrict__ cursor,
                        const float* __restrict__ x,
                        int* __restrict__ rowpack, float* __restrict__ dinv,
                        float4* __restrict__ xd, int* __restrict__ csr) {
    __shared__ __align__(16) int lcsr[CAP];
    __shared__ int hcnt[BNODES];
    __shared__ int off[BNODES];
    __shared__ int wsum[4];
    int b = blockIdx.x, tid = threadIdx.x;
    int node0 = b << BSH;
    int s0 = b * CAP;
    int ec = cursor[b];
    hcnt[tid] = 0;
    __syncthreads();
    int ctail = ec & ~3;
    for (int i = tid * 4; i < ctail; i += 1024) {      // int4 vector hist pass
        int4 p = *(const int4*)(part + s0 + i);
        atomicAdd(&hcnt[p.x & (BNODES - 1)], 1);
        atomicAdd(&hcnt[p.y & (BNODES - 1)], 1);
        atomicAdd(&hcnt[p.z & (BNODES - 1)], 1);
        atomicAdd(&hcnt[p.w & (BNODES - 1)], 1);
    }
    if (tid < ec - ctail) atomicAdd(&hcnt[part[s0 + ctail + tid] & (BNODES - 1)], 1);
    __syncthreads();
    int c = hcnt[tid];
    int v = c;
#pragma unroll
    for (int o = 1; o < 64; o <<= 1) {
        int t = __shfl_up(v, o, 64);
        if ((tid & 63) >= o) v += t;
    }
    if ((tid & 63) == 63) wsum[tid >> 6] = v;
    __syncthreads();
    int add = 0;
    for (int w = 0; w < (tid >> 6); ++w) add += wsum[w];
    int excl = v + add - c;
    int n = node0 + tid;
    if (n < NN) {
        rowpack[n] = ((s0 + excl) << 10) | c;
        float d = rsqrtf((float)c + 1.0f);
        dinv[n] = d;
        xd[n] = make_float4(d * x[n * 3 + 0], d * x[n * 3 + 1], d * x[n * 3 + 2], d);
    }
    off[tid] = excl;
    __syncthreads();
    for (int i = tid * 4; i < ctail; i += 1024) {      // int4 rank-scatter (part cache-hot)
        int4 p = *(const int4*)(part + s0 + i);
        { int pos = atomicAdd(&off[p.x & (BNODES - 1)], 1); lcsr[pos] = p.x >> 8; }
        { int pos = atomicAdd(&off[p.y & (BNODES - 1)], 1); lcsr[pos] = p.y >> 8; }
        { int pos = atomicAdd(&off[p.z & (BNODES - 1)], 1); lcsr[pos] = p.z >> 8; }
        { int pos = atomicAdd(&off[p.w & (BNODES - 1)], 1); lcsr[pos] = p.w >> 8; }
    }
    if (tid < ec - ctail) {
        int p = part[s0 + ctail + tid];
        int pos = atomicAdd(&off[p & (BNODES - 1)], 1);
        lcsr[pos] = p >> 8;
    }
    __syncthreads();
    for (int i = tid * 4; i < ctail; i += 1024)        // int4 coalesced write-out
        *(int4*)(csr + s0 + i) = *(const int4*)(lcsr + i);
    if (tid < ec - ctail) csr[s0 + ctail + tid] = lcsr[ctail + tid];
}

// ---- l1: 8 lanes/node gather + shfl-reduce + fused W1/relu -> g1 fp16 (coalesced) ----
// g1[n] = dinv[n] * relu( (dinv[n]*(sum_e xd[s]+xd[n])) @ W1 + b1 )
#define L1NPB 32                               // nodes per 256-thread block
__global__ void k_l1(const int* __restrict__ rowpack, const int* __restrict__ csr,
                     const float4* __restrict__ xd,
                     const float* __restrict__ W1, const float* __restrict__ b1,
                     __half2* __restrict__ g1) {
    __shared__ float W1s[3 * F];
    __shared__ float b1s[F];
    int tid = threadIdx.x;
    if (tid < 3 * F) W1s[tid] = W1[tid];
    if (tid < F) b1s[tid] = b1[tid];
    __syncthreads();
    int nl = tid >> 3, l8 = tid & 7;
    int n = blockIdx.x * L1NPB + nl;
    if (n >= NN) return;
    int pack = rowpack[n];
    int beg = pack >> 10, deg = pack & 1023;
    float ax = 0.0f, ay = 0.0f, az = 0.0f;
    for (int e = beg + l8; e < beg + deg; e += 8) {     // 8-lane edge stride, 32B csr reads
        float4 v = xd[csr[e]];
        ax += v.x; ay += v.y; az += v.z;
    }
#pragma unroll
    for (int o = 1; o < 8; o <<= 1) {                   // xor-reduce: all 8 lanes get sums
        ax += __shfl_xor(ax, o, 8);
        ay += __shfl_xor(ay, o, 8);
        az += __shfl_xor(az, o, 8);
    }
    float4 sf = xd[n];
    float dn = sf.w;
    float cx = dn * (ax + sf.x), cy = dn * (ay + sf.y), cz = dn * (az + sf.z);
    // each lane computes 4 features -> one uint2 (8B); 8 lanes = 64B coalesced row
    __half2 tmp[2];
#pragma unroll
    for (int t = 0; t < 2; ++t) {
        int f0 = l8 * 4 + 2 * t, f1 = f0 + 1;
        float v0 = cx * W1s[f0] + cy * W1s[F + f0] + cz * W1s[2 * F + f0] + b1s[f0];
        float v1 = cx * W1s[f1] + cy * W1s[F + f1] + cz * W1s[2 * F + f1] + b1s[f1];
        tmp[t] = __floats2half2_rn(dn * fmaxf(v0, 0.0f), dn * fmaxf(v1, 0.0f));
    }
    *(uint2*)(g1 + (size_t)n * 16 + l8 * 2) = *(const uint2*)tmp;
}

// ---- gather2p: gather g1 + fp32 t + proj2(W2)+relu + per-block pool -> gsum ----
__global__ void k_gather2p(const int* __restrict__ rowpack, const int* __restrict__ csr,
                           const __half2* __restrict__ g1, const float* __restrict__ dinv,
                           const int* __restrict__ batch,
                           const float* __restrict__ W2, const float* __restrict__ b2,
                           float* __restrict__ gsum) {
    __shared__ __align__(16) float W2s[F * F];
    __shared__ __align__(16) float b2s[F];
    __shared__ float ts[16][F];
    __shared__ float hs[16][F];
    __shared__ int bat[16];
    int tid = threadIdx.x;
    int nb = blockIdx.x * 16;
    ((float4*)W2s)[tid] = ((const float4*)W2)[tid];    // 256 threads x float4 = 1024 floats
    if (tid < F / 4) ((float4*)b2s)[tid] = ((const float4*)b2)[tid];
    if (tid < 16) bat[tid] = batch[nb + tid];
    int nl = tid >> 4, j = tid & 15;
    int n = nb + nl;
    {
        int pack = rowpack[n];
        int beg = pack >> 10, end = beg + (pack & 1023);
        float ax = 0.0f, ay = 0.0f;
        int e = beg;
        for (; e + 7 < end; e += 8) {
            int s0 = csr[e],     s1 = csr[e + 1], s2 = csr[e + 2], s3 = csr[e + 3];
            int s4 = csr[e + 4], s5 = csr[e + 5], s6 = csr[e + 6], s7 = csr[e + 7];
            float2 v0 = __half22float2(g1[s0 * 16 + j]);
            float2 v1 = __half22float2(g1[s1 * 16 + j]);
            float2 v2 = __half22float2(g1[s2 * 16 + j]);
            float2 v3 = __half22float2(g1[s3 * 16 + j]);
            float2 v4 = __half22float2(g1[s4 * 16 + j]);
            float2 v5 = __half22float2(g1[s5 * 16 + j]);
            float2 v6 = __half22float2(g1[s6 * 16 + j]);
            float2 v7 = __half22float2(g1[s7 * 16 + j]);
            ax += ((v0.x + v1.x) + (v2.x + v3.x)) + ((v4.x + v5.x) + (v6.x + v7.x));
            ay += ((v0.y + v1.y) + (v2.y + v3.y)) + ((v4.y + v5.y) + (v6.y + v7.y));
        }
        for (; e + 3 < end; e += 4) {
            int s0 = csr[e], s1 = csr[e + 1], s2 = csr[e + 2], s3 = csr[e + 3];
            float2 v0 = __half22float2(g1[s0 * 16 + j]);
            float2 v1 = __half22float2(g1[s1 * 16 + j]);
            float2 v2 = __half22float2(g1[s2 * 16 + j]);
            float2 v3 = __half22float2(g1[s3 * 16 + j]);
            ax += (v0.x + v1.x) + (v2.x + v3.x);
            ay += (v0.y + v1.y) + (v2.y + v3.y);
        }
        for (; e < end; ++e) {
            float2 v = __half22float2(g1[csr[e] * 16 + j]);
            ax += v.x; ay += v.y;
        }
        float dn = dinv[n];
        float2 sf = __half22float2(g1[n * 16 + j]);
        ts[nl][2 * j]     = dn * (ax + sf.x);
        ts[nl][2 * j + 1] = dn * (ay + sf.y);
    }
    __syncthreads();
    {
        int f = tid & 31;
        int nn0 = tid >> 5;           // 0..7
#pragma unroll
        for (int pass = 0; pass < 2; ++pass) {
            int nn = nn0 + pass * 8;
            float acc = b2s[f];
#pragma unroll
            for (int k = 0; k < F; ++k) acc += ts[nn][k] * W2s[k * F + f];
            hs[nn][f] = fmaxf(acc, 0.0f);
        }
    }
    __syncthreads();
    if (tid < F) {
        int g0 = bat[0], gmax = bat[15];
        for (int g = g0; g <= gmax; ++g) {
            float s = 0.0f;
#pragma unroll
            for (int i = 0; i < 16; ++i) if (bat[i] == g) s += hs[i][tid];
            atomicAdd(&gsum[g * F + tid], s);
        }
    }
}

// ---- head: out[g] = (gsum[g]/max(cnt,1)) @ Wl + bl ----
__global__ void k_head(const float* __restrict__ gsum, const int* __restrict__ batch,
                       const float* __restrict__ Wl, const float* __restrict__ bl,
                       float* __restrict__ out) {
    int g = blockIdx.x * blockDim.x + threadIdx.x;
    if (g >= NG) return;
    int lo = 0, hi = NN;
    while (lo < hi) { int m = (lo + hi) >> 1; if (batch[m] < g) lo = m + 1; else hi = m; }
    int s = lo;
    lo = 0; hi = NN;
    while (lo < hi) { int m = (lo + hi) >> 1; if (batch[m] < g + 1) lo = m + 1; else hi = m; }
    float inv = 1.0f / fmaxf((float)(lo - s), 1.0f);
    float a0 = 0.0f, a1 = 0.0f;
#pragma unroll
    for (int k = 0; k < F; ++k) {
        float m = gsum[g * F + k] * inv;
        a0 += m * Wl[k * 2 + 0];
        a1 += m * Wl[k * 2 + 1];
    }
    out[g * 2 + 0] = a0 + bl[0];
    out[g * 2 + 1] = a1 + bl[1];
}

extern "C" void kernel_launch(void* const* d_in, const int* in_sizes, int n_in,
                              void* d_out, int out_size, void* d_ws, size_t ws_size,
                              hipStream_t stream) {
    const float* x     = (const float*)d_in[0];
    const int*   eidx  = (const int*)d_in[1];   // int32 per harness contract
    const int*   batch = (const int*)d_in[2];
    const float* W1    = (const float*)d_in[3];
    const float* b1    = (const float*)d_in[4];
    const float* W2    = (const float*)d_in[5];
    const float* b2    = (const float*)d_in[6];
    const float* Wl    = (const float*)d_in[7];
    const float* bl    = (const float*)d_in[8];
    float*       out   = (float*)d_out;

    const int* src = eidx;
    const int* dst = eidx + NE;

    // ---- workspace layout, 128B-aligned chunks ----
    char* base = (char*)d_ws;
    size_t off = 0;
    auto alloc = [&](size_t bytes) {
        void* p = base + off;
        off = (off + bytes + 127) & ~(size_t)127;
        return p;
    };
    // cursor + gsum contiguous -> single memset
    int*     cursor  = (int*)alloc(NB * sizeof(int) + (size_t)NG * F * sizeof(float));
    float*   gsum    = (float*)(cursor + NB);
    int*     rowpack = (int*)alloc(NN * sizeof(int));
    int*     part    = (int*)alloc((size_t)NB * CAP * sizeof(int));
    int*     csr     = (int*)alloc((size_t)NB * CAP * sizeof(int));
    float*   dinv    = (float*)alloc(NN * sizeof(float));
    float4*  xd      = (float4*)alloc(NN * sizeof(float4));
    __half2* g1      = (__half2*)alloc((size_t)NN * 16 * sizeof(__half2));

    const int B = 256;
    const int gL1  = (NN + L1NPB - 1) / L1NPB;   // 3125
    const int gG16 = NN / 16;                    // 6250, exact

    hipMemsetAsync(cursor, 0, NB * sizeof(int) + (size_t)NG * F * sizeof(float), stream);

    // ---- CSR build (2 kernels) ----
    k_partition<<<NWGP, 512, 0, stream>>>(src, dst, cursor, part);
    k_build    <<<NB,   B,   0, stream>>>(part, cursor, x, rowpack, dinv, xd, csr);

    // ---- layer 1 (8 lanes/node, latency-hidden) ----
    k_l1<<<gL1, B, 0, stream>>>(rowpack, csr, xd, W1, b1, g1);

    // ---- layer 2 gather + proj2 + relu + pool (fused) ----
    k_gather2p<<<gG16, B, 0, stream>>>(rowpack, csr, g1, dinv, batch, W2, b2, gsum);

    // ---- head ----
    k_head<<<(NG + B - 1) / B, B, 0, stream>>>(gsum, batch, Wl, bl, out);
}

// Round 6
// 153.872 us; speedup vs baseline: 3.2908x; 1.0189x over previous
//
#include <hip/hip_runtime.h>
#include <hip/hip_fp16.h>

#define NN 100000
#define NE 1600000
#define NG 512
#define F  32

#define BSH    8                              // 256 dst-nodes per bucket
#define BNODES 256
#define NB     ((NN + BNODES - 1) / BNODES)   // 391
#define CAP    5120                           // slots/bucket (mean 4092, sigma 64 -> safe)
#define PCHUNK 4096
#define EPT    8                              // edges per thread (PCHUNK/512)
#define NWGP   ((NE + PCHUNK - 1) / PCHUNK)   // 391

// ---- partition: in-LDS counting sort per chunk -> coalesced bucket-run writes ----
__global__ void k_partition(const int* __restrict__ src, const int* __restrict__ dst,
                            int* __restrict__ cursor, int* __restrict__ part) {
    __shared__ int   s_cnt[NB];      // hist, then reused as rank counter
    __shared__ int   s_lstart[NB];
    __shared__ int   s_base[NB];
    __shared__ int   wsum[8];
    __shared__ int   lsort[PCHUNK];
    __shared__ short lbkt[PCHUNK];
    int tid = threadIdx.x;
    for (int i = tid; i < NB; i += 512) s_cnt[i] = 0;
    __syncthreads();
    int e0 = blockIdx.x * PCHUNK;
    int rem = NE - e0;
    int pk[EPT]; short bk[EPT];
    int m = 0;
    if (rem >= PCHUNK) {
        // full chunk: 2x int4 vector loads per thread (16B/lane, fully coalesced)
#pragma unroll
        for (int h = 0; h < 2; ++h) {
            int e = e0 + h * 2048 + tid * 4;
            int4 s4 = *(const int4*)(src + e);
            int4 d4 = *(const int4*)(dst + e);
            int ss[4] = {s4.x, s4.y, s4.z, s4.w};
            int dd[4] = {d4.x, d4.y, d4.z, d4.w};
#pragma unroll
            for (int u = 0; u < 4; ++u) {
                pk[m] = (ss[u] << 8) | (dd[u] & (BNODES - 1));
                bk[m] = (short)(dd[u] >> BSH);
                atomicAdd(&s_cnt[bk[m]], 1);
                ++m;
            }
        }
    } else {
        // tail chunk (2560 edges): scalar guarded path
#pragma unroll
        for (int k = 0; k < EPT; ++k) {
            int e = e0 + tid + k * 512;
            if (e < NE) {
                int d = dst[e];
                pk[m] = (src[e] << 8) | (d & (BNODES - 1));
                bk[m] = (short)(d >> BSH);
                atomicAdd(&s_cnt[bk[m]], 1);
                ++m;
            }
        }
    }
    __syncthreads();
    int cv = (tid < NB) ? s_cnt[tid] : 0;
    int v = cv;
#pragma unroll
    for (int o = 1; o < 64; o <<= 1) {
        int t = __shfl_up(v, o, 64);
        if ((tid & 63) >= o) v += t;
    }
    if ((tid & 63) == 63) wsum[tid >> 6] = v;
    __syncthreads();
    int add = 0;
    for (int w = 0; w < (tid >> 6); ++w) add += wsum[w];
    int excl = v + add - cv;
    if (tid < NB) {
        s_lstart[tid] = excl;
        if (cv) s_base[tid] = tid * CAP + atomicAdd(&cursor[tid], cv);
        s_cnt[tid] = 0;   // reuse as rank counter
    }
    __syncthreads();
    for (int k = 0; k < m; ++k) {
        int b = bk[k];
        int r = s_lstart[b] + atomicAdd(&s_cnt[b], 1);
        lsort[r] = pk[k];
        lbkt[r]  = (short)b;
    }
    __syncthreads();
    int cnt = min(rem, PCHUNK);
    for (int i = tid; i < cnt; i += 512) {
        int b = lbkt[i];
        part[s_base[b] + (i - s_lstart[b])] = lsort[i];   // coalesced per-bucket runs
    }
}

// ---- build: hist + scan -> rowpack/dinv/xd, then rank-scatter + coalesced csr write ----
__global__ void k_build(const int* __restrict__ part, const int* __restrict__ cursor,
                        const float* __restrict__ x,
                        int* __restrict__ rowpack, float* __restrict__ dinv,
                        float4* __restrict__ xd, int* __restrict__ csr) {
    __shared__ __align__(16) int lcsr[CAP];
    __shared__ int hcnt[BNODES];
    __shared__ int off[BNODES];
    __shared__ int wsum[4];
    int b = blockIdx.x, tid = threadIdx.x;
    int node0 = b << BSH;
    int s0 = b * CAP;
    int ec = cursor[b];
    hcnt[tid] = 0;
    __syncthreads();
    int ctail = ec & ~3;
    for (int i = tid * 4; i < ctail; i += 1024) {      // int4 vector hist pass
        int4 p = *(const int4*)(part + s0 + i);
        atomicAdd(&hcnt[p.x & (BNODES - 1)], 1);
        atomicAdd(&hcnt[p.y & (BNODES - 1)], 1);
        atomicAdd(&hcnt[p.z & (BNODES - 1)], 1);
        atomicAdd(&hcnt[p.w & (BNODES - 1)], 1);
    }
    if (tid < ec - ctail) atomicAdd(&hcnt[part[s0 + ctail + tid] & (BNODES - 1)], 1);
    __syncthreads();
    int c = hcnt[tid];
    int v = c;
#pragma unroll
    for (int o = 1; o < 64; o <<= 1) {
        int t = __shfl_up(v, o, 64);
        if ((tid & 63) >= o) v += t;
    }
    if ((tid & 63) == 63) wsum[tid >> 6] = v;
    __syncthreads();
    int add = 0;
    for (int w = 0; w < (tid >> 6); ++w) add += wsum[w];
    int excl = v + add - c;
    int n = node0 + tid;
    if (n < NN) {
        rowpack[n] = ((s0 + excl) << 10) | c;
        float d = rsqrtf((float)c + 1.0f);
        dinv[n] = d;
        xd[n] = make_float4(d * x[n * 3 + 0], d * x[n * 3 + 1], d * x[n * 3 + 2], d);
    }
    off[tid] = excl;
    __syncthreads();
    for (int i = tid * 4; i < ctail; i += 1024) {      // int4 rank-scatter (part cache-hot)
        int4 p = *(const int4*)(part + s0 + i);
        { int pos = atomicAdd(&off[p.x & (BNODES - 1)], 1); lcsr[pos] = p.x >> 8; }
        { int pos = atomicAdd(&off[p.y & (BNODES - 1)], 1); lcsr[pos] = p.y >> 8; }
        { int pos = atomicAdd(&off[p.z & (BNODES - 1)], 1); lcsr[pos] = p.z >> 8; }
        { int pos = atomicAdd(&off[p.w & (BNODES - 1)], 1); lcsr[pos] = p.w >> 8; }
    }
    if (tid < ec - ctail) {
        int p = part[s0 + ctail + tid];
        int pos = atomicAdd(&off[p & (BNODES - 1)], 1);
        lcsr[pos] = p >> 8;
    }
    __syncthreads();
    for (int i = tid * 4; i < ctail; i += 1024)        // int4 coalesced write-out
        *(int4*)(csr + s0 + i) = *(const int4*)(lcsr + i);
    if (tid < ec - ctail) csr[s0 + ctail + tid] = lcsr[ctail + tid];
}

// ---- l1: 8 lanes/node gather + shfl-reduce + fused W1/relu -> g1 fp16 (coalesced) ----
#define L1NPB 32                               // nodes per 256-thread block
__global__ void k_l1(const int* __restrict__ rowpack, const int* __restrict__ csr,
                     const float4* __restrict__ xd,
                     const float* __restrict__ W1, const float* __restrict__ b1,
                     __half2* __restrict__ g1) {
    __shared__ float W1s[3 * F];
    __shared__ float b1s[F];
    int tid = threadIdx.x;
    if (tid < 3 * F) W1s[tid] = W1[tid];
    if (tid < F) b1s[tid] = b1[tid];
    __syncthreads();
    int nl = tid >> 3, l8 = tid & 7;
    int n = blockIdx.x * L1NPB + nl;
    if (n >= NN) return;
    int pack = rowpack[n];
    int beg = pack >> 10, deg = pack & 1023;
    float ax = 0.0f, ay = 0.0f, az = 0.0f;
    for (int e = beg + l8; e < beg + deg; e += 8) {     // 8-lane edge stride
        float4 v = xd[csr[e]];
        ax += v.x; ay += v.y; az += v.z;
    }
#pragma unroll
    for (int o = 1; o < 8; o <<= 1) {                   // xor-reduce: all 8 lanes get sums
        ax += __shfl_xor(ax, o, 8);
        ay += __shfl_xor(ay, o, 8);
        az += __shfl_xor(az, o, 8);
    }
    float4 sf = xd[n];
    float dn = sf.w;
    float cx = dn * (ax + sf.x), cy = dn * (ay + sf.y), cz = dn * (az + sf.z);
    __half2 tmp[2];
#pragma unroll
    for (int t = 0; t < 2; ++t) {
        int f0 = l8 * 4 + 2 * t, f1 = f0 + 1;
        float v0 = cx * W1s[f0] + cy * W1s[F + f0] + cz * W1s[2 * F + f0] + b1s[f0];
        float v1 = cx * W1s[f1] + cy * W1s[F + f1] + cz * W1s[2 * F + f1] + b1s[f1];
        tmp[t] = __floats2half2_rn(dn * fmaxf(v0, 0.0f), dn * fmaxf(v1, 0.0f));
    }
    *(uint2*)(g1 + (size_t)n * 16 + l8 * 2) = *(const uint2*)tmp;
}

// ---- gather2p: LDS-staged csr segment + gather g1 + proj2(W2)+relu + pool -> gsum ----
// block's 16 consecutive nodes live in one bucket => one contiguous csr segment.
#define SEGCAP 1024
__global__ void k_gather2p(const int* __restrict__ rowpack, const int* __restrict__ csr,
                           const __half2* __restrict__ g1, const float* __restrict__ dinv,
                           const int* __restrict__ batch,
                           const float* __restrict__ W2, const float* __restrict__ b2,
                           float* __restrict__ gsum) {
    __shared__ __align__(16) float W2s[F * F];
    __shared__ __align__(16) float b2s[F];
    __shared__ float ts[16][F];
    __shared__ float hs[16][F];
    __shared__ int bat[16];
    __shared__ int lc[SEGCAP];
    int tid = threadIdx.x;
    int nb = blockIdx.x * 16;
    ((float4*)W2s)[tid] = ((const float4*)W2)[tid];    // 256 threads x float4 = 1024 floats
    if (tid < F / 4) ((float4*)b2s)[tid] = ((const float4*)b2)[tid];
    if (tid < 16) bat[tid] = batch[nb + tid];
    // ---- stage the block's contiguous csr segment into LDS (coalesced once) ----
    int rp0  = rowpack[nb];
    int rp15 = rowpack[nb + 15];
    int beg0 = rp0 >> 10;
    int seg  = (rp15 >> 10) + (rp15 & 1023) - beg0;
    bool useLds = (seg <= SEGCAP);               // stats: seg ~ 256±16; guard anyway
    if (useLds) {
        for (int i = tid; i < seg; i += 256) lc[i] = csr[beg0 + i];
    }
    __syncthreads();
    int nl = tid >> 4, j = tid & 15;
    int n = nb + nl;
    {
        int pack = rowpack[n];
        int deg = pack & 1023;
        float ax = 0.0f, ay = 0.0f;
        if (useLds) {
            int e = (pack >> 10) - beg0;
            int end = e + deg;
            for (; e + 7 < end; e += 8) {
                int s0 = lc[e],     s1 = lc[e + 1], s2 = lc[e + 2], s3 = lc[e + 3];
                int s4 = lc[e + 4], s5 = lc[e + 5], s6 = lc[e + 6], s7 = lc[e + 7];
                float2 v0 = __half22float2(g1[s0 * 16 + j]);
                float2 v1 = __half22float2(g1[s1 * 16 + j]);
                float2 v2 = __half22float2(g1[s2 * 16 + j]);
                float2 v3 = __half22float2(g1[s3 * 16 + j]);
                float2 v4 = __half22float2(g1[s4 * 16 + j]);
                float2 v5 = __half22float2(g1[s5 * 16 + j]);
                float2 v6 = __half22float2(g1[s6 * 16 + j]);
                float2 v7 = __half22float2(g1[s7 * 16 + j]);
                ax += ((v0.x + v1.x) + (v2.x + v3.x)) + ((v4.x + v5.x) + (v6.x + v7.x));
                ay += ((v0.y + v1.y) + (v2.y + v3.y)) + ((v4.y + v5.y) + (v6.y + v7.y));
            }
            for (; e + 3 < end; e += 4) {
                int s0 = lc[e], s1 = lc[e + 1], s2 = lc[e + 2], s3 = lc[e + 3];
                float2 v0 = __half22float2(g1[s0 * 16 + j]);
                float2 v1 = __half22float2(g1[s1 * 16 + j]);
                float2 v2 = __half22float2(g1[s2 * 16 + j]);
                float2 v3 = __half22float2(g1[s3 * 16 + j]);
                ax += (v0.x + v1.x) + (v2.x + v3.x);
                ay += (v0.y + v1.y) + (v2.y + v3.y);
            }
            for (; e < end; ++e) {
                float2 v = __half22float2(g1[lc[e] * 16 + j]);
                ax += v.x; ay += v.y;
            }
        } else {                                   // never in practice; correctness guard
            int e = pack >> 10;
            int end = e + deg;
            for (; e < end; ++e) {
                float2 v = __half22float2(g1[csr[e] * 16 + j]);
                ax += v.x; ay += v.y;
            }
        }
        float dn = dinv[n];
        float2 sf = __half22float2(g1[n * 16 + j]);
        ts[nl][2 * j]     = dn * (ax + sf.x);
        ts[nl][2 * j + 1] = dn * (ay + sf.y);
    }
    __syncthreads();
    {
        int f = tid & 31;
        int nn0 = tid >> 5;           // 0..7
#pragma unroll
        for (int pass = 0; pass < 2; ++pass) {
            int nn = nn0 + pass * 8;
            float acc = b2s[f];
#pragma unroll
            for (int k = 0; k < F; ++k) acc += ts[nn][k] * W2s[k * F + f];
            hs[nn][f] = fmaxf(acc, 0.0f);
        }
    }
    __syncthreads();
    if (tid < F) {
        int g0 = bat[0], gmax = bat[15];
        for (int g = g0; g <= gmax; ++g) {
            float s = 0.0f;
#pragma unroll
            for (int i = 0; i < 16; ++i) if (bat[i] == g) s += hs[i][tid];
            atomicAdd(&gsum[g * F + tid], s);
        }
    }
}

// ---- head: out[g] = (gsum[g]/max(cnt,1)) @ Wl + bl ----
__global__ void k_head(const float* __restrict__ gsum, const int* __restrict__ batch,
                       const float* __restrict__ Wl, const float* __restrict__ bl,
                       float* __restrict__ out) {
    int g = blockIdx.x * blockDim.x + threadIdx.x;
    if (g >= NG) return;
    int lo = 0, hi = NN;
    while (lo < hi) { int m = (lo + hi) >> 1; if (batch[m] < g) lo = m + 1; else hi = m; }
    int s = lo;
    lo = 0; hi = NN;
    while (lo < hi) { int m = (lo + hi) >> 1; if (batch[m] < g + 1) lo = m + 1; else hi = m; }
    float inv = 1.0f / fmaxf((float)(lo - s), 1.0f);
    float a0 = 0.0f, a1 = 0.0f;
#pragma unroll
    for (int k = 0; k < F; ++k) {
        float m = gsum[g * F + k] * inv;
        a0 += m * Wl[k * 2 + 0];
        a1 += m * Wl[k * 2 + 1];
    }
    out[g * 2 + 0] = a0 + bl[0];
    out[g * 2 + 1] = a1 + bl[1];
}

extern "C" void kernel_launch(void* const* d_in, const int* in_sizes, int n_in,
                              void* d_out, int out_size, void* d_ws, size_t ws_size,
                              hipStream_t stream) {
    const float* x     = (const float*)d_in[0];
    const int*   eidx  = (const int*)d_in[1];   // int32 per harness contract
    const int*   batch = (const int*)d_in[2];
    const float* W1    = (const float*)d_in[3];
    const float* b1    = (const float*)d_in[4];
    const float* W2    = (const float*)d_in[5];
    const float* b2    = (const float*)d_in[6];
    const float* Wl    = (const float*)d_in[7];
    const float* bl    = (const float*)d_in[8];
    float*       out   = (float*)d_out;

    const int* src = eidx;
    const int* dst = eidx + NE;

    // ---- workspace layout, 128B-aligned chunks ----
    char* base = (char*)d_ws;
    size_t off = 0;
    auto alloc = [&](size_t bytes) {
        void* p = base + off;
        off = (off + bytes + 127) & ~(size_t)127;
        return p;
    };
    // cursor + gsum contiguous -> single memset
    int*     cursor  = (int*)alloc(NB * sizeof(int) + (size_t)NG * F * sizeof(float));
    float*   gsum    = (float*)(cursor + NB);
    int*     rowpack = (int*)alloc(NN * sizeof(int));
    int*     part    = (int*)alloc((size_t)NB * CAP * sizeof(int));
    int*     csr     = (int*)alloc((size_t)NB * CAP * sizeof(int));
    float*   dinv    = (float*)alloc(NN * sizeof(float));
    float4*  xd      = (float4*)alloc(NN * sizeof(float4));
    __half2* g1      = (__half2*)alloc((size_t)NN * 16 * sizeof(__half2));

    const int B = 256;
    const int gL1  = (NN + L1NPB - 1) / L1NPB;   // 3125
    const int gG16 = NN / 16;                    // 6250, exact

    hipMemsetAsync(cursor, 0, NB * sizeof(int) + (size_t)NG * F * sizeof(float), stream);

    // ---- CSR build (2 kernels) ----
    k_partition<<<NWGP, 512, 0, stream>>>(src, dst, cursor, part);
    k_build    <<<NB,   B,   0, stream>>>(part, cursor, x, rowpack, dinv, xd, csr);

    // ---- layer 1 (8 lanes/node, latency-hidden) ----
    k_l1<<<gL1, B, 0, stream>>>(rowpack, csr, xd, W1, b1, g1);

    // ---- layer 2 gather + proj2 + relu + pool (fused, LDS-staged csr) ----
    k_gather2p<<<gG16, B, 0, stream>>>(rowpack, csr, g1, dinv, batch, W2, b2, gsum);

    // ---- head ----
    k_head<<<(NG + B - 1) / B, B, 0, stream>>>(gsum, batch, Wl, bl, out);
}